// Round 1
// baseline (1611.381 us; speedup 1.0000x reference)
//
#include <hip/hip_runtime.h>
#include <math.h>

#define BSZ 32
#define NUM_KV 8
#define HEAD_DIM 128
#define HIDDEN 4096
#define MAX_SEQ 4096
#define QKV_OUT 6144
#define SCALEF 0.08838834764831845f

// ---------------- batched-GEMV (skinny GEMM): part[split][b][j] = sum_h W[j][h]*X[b][h] ----------
// block: 256 threads; covers 64 j x 32 b; thread-tile 4j x 4b; h split across blocks (4 splits of 1024)
// j mapping: j = j0 + jg + 16*jj (keeps LDS bank spread with stride 132)
constexpr int HLEN = 1024;
constexpr int HCHUNK = 128;

__global__ __launch_bounds__(256) void gemv_bk(
    const float* __restrict__ W, const float* __restrict__ X,
    float* __restrict__ part, int J, int njt)
{
  int jt = blockIdx.x % njt;
  int split = blockIdx.x / njt;
  int j0 = jt * 64;
  int h0 = split * HLEN;

  __shared__ __align__(16) float Wt[64 * 132];
  __shared__ __align__(16) float Xt[BSZ * 132];

  int tid = threadIdx.x;
  int hs = tid >> 7;          // 0/1: which half of each h-chunk
  int jg = (tid >> 3) & 15;   // 0..15
  int bg = tid & 7;           // 0..7

  float acc[4][4] = {{0.f,0.f,0.f,0.f},{0.f,0.f,0.f,0.f},{0.f,0.f,0.f,0.f},{0.f,0.f,0.f,0.f}};

  for (int hc = 0; hc < HLEN; hc += HCHUNK) {
    const float* Wg = W + (size_t)j0 * HIDDEN + h0 + hc;
    #pragma unroll
    for (int it = 0; it < 8; it++) {
      int f = tid + it * 256;
      int r = f >> 5, c = f & 31;
      *(float4*)(Wt + r * 132 + 4 * c) = *(const float4*)(Wg + (size_t)r * HIDDEN + 4 * c);
    }
    const float* Xg = X + h0 + hc;
    #pragma unroll
    for (int it = 0; it < 4; it++) {
      int f = tid + it * 256;
      int r = f >> 5, c = f & 31;
      *(float4*)(Xt + r * 132 + 4 * c) = *(const float4*)(Xg + (size_t)r * HIDDEN + 4 * c);
    }
    __syncthreads();

    int hbase = hs * 64;
    #pragma unroll 4
    for (int hh = 0; hh < 64; hh += 4) {
      int ho = hbase + hh;
      float4 xv[4], wv[4];
      #pragma unroll
      for (int bb = 0; bb < 4; bb++)
        xv[bb] = *(const float4*)(Xt + (bg + 8 * bb) * 132 + ho);
      #pragma unroll
      for (int jj = 0; jj < 4; jj++)
        wv[jj] = *(const float4*)(Wt + (jg + 16 * jj) * 132 + ho);
      #pragma unroll
      for (int jj = 0; jj < 4; jj++)
        #pragma unroll
        for (int bb = 0; bb < 4; bb++)
          acc[jj][bb] += wv[jj].x * xv[bb].x + wv[jj].y * xv[bb].y +
                         wv[jj].z * xv[bb].z + wv[jj].w * xv[bb].w;
    }
    __syncthreads();
  }

  // reduce the two hs halves through LDS (reuse Wt)
  int slot = jg * 8 + bg;
  if (hs == 1) {
    #pragma unroll
    for (int jj = 0; jj < 4; jj++)
      #pragma unroll
      for (int bb = 0; bb < 4; bb++)
        Wt[slot * 16 + jj * 4 + bb] = acc[jj][bb];
  }
  __syncthreads();
  if (hs == 0) {
    #pragma unroll
    for (int jj = 0; jj < 4; jj++)
      #pragma unroll
      for (int bb = 0; bb < 4; bb++) {
        float v = acc[jj][bb] + Wt[slot * 16 + jj * 4 + bb];
        part[((size_t)split * BSZ + (bg + 8 * bb)) * J + j0 + jg + 16 * jj] = v;
      }
  }
}

// ---------------- finalize QKV: sum 4 h-split partials + bias, scatter q->ws, k/v->cache --------
__global__ __launch_bounds__(256) void finalize_qkv(
    const float* __restrict__ part, const float* __restrict__ bqkv,
    float* __restrict__ qws, float* __restrict__ kvc, const int* __restrict__ slot)
{
  int idx = blockIdx.x * 256 + threadIdx.x;   // 32*6144
  int b = idx / QKV_OUT;
  int j = idx - b * QKV_OUT;
  float v = part[((size_t)0 * BSZ + b) * QKV_OUT + j]
          + part[((size_t)1 * BSZ + b) * QKV_OUT + j]
          + part[((size_t)2 * BSZ + b) * QKV_OUT + j]
          + part[((size_t)3 * BSZ + b) * QKV_OUT + j]
          + bqkv[j];
  if (j < 4096) {
    qws[(size_t)b * 4096 + j] = v;
  } else if (j < 5120) {
    int d = j - 4096; int kh = d >> 7; int dd = d & 127;
    kvc[(((size_t)b * MAX_SEQ + slot[b]) * NUM_KV + kh) * HEAD_DIM + dd] = v;
  } else {
    int d = j - 5120; int kh = d >> 7; int dd = d & 127;
    kvc[((((size_t)BSZ + b) * MAX_SEQ + slot[b]) * NUM_KV + kh) * HEAD_DIM + dd] = v;
  }
}

// ---------------- flash-decode attention, split over sequence ---------------------------------
constexpr int NSPLIT_S = 8;
constexpr int SLEN = 512;

__global__ __launch_bounds__(256) void attn_kernel(
    const float* __restrict__ kvc, const float* __restrict__ qws,
    const int* __restrict__ seq_lens, float* __restrict__ po, float* __restrict__ pml)
{
  int split = blockIdx.x & 7;
  int kvh = (blockIdx.x >> 3) & 7;
  int b = blockIdx.x >> 6;
  int tid = threadIdx.x;
  int g = tid >> 6;          // head-in-group 0..3
  int lane = tid & 63;
  size_t pbase = (((size_t)split * BSZ + b) * NUM_KV + kvh) * 4 + g;

  int sl = seq_lens[b];
  int s0 = split * SLEN;
  int n = min(sl - s0, SLEN);
  if (n <= 0) {
    po[pbase * HEAD_DIM + 2 * lane]     = 0.f;
    po[pbase * HEAD_DIM + 2 * lane + 1] = 0.f;
    if (lane == 0) { pml[pbase * 2] = -INFINITY; pml[pbase * 2 + 1] = 0.f; }
    return;
  }

  __shared__ __align__(16) float ql[4 * HEAD_DIM];
  __shared__ float sc[4 * SLEN];
  if (tid < 128)
    *(float4*)(ql + tid * 4) = *(const float4*)(qws + (size_t)b * 4096 + kvh * 512 + tid * 4);
  __syncthreads();

  // phase A: scores (thread per s; 4 heads per thread; q via LDS broadcast)
  const float* K = kvc + (((size_t)b * MAX_SEQ + s0) * NUM_KV + kvh) * HEAD_DIM;
  for (int i = tid; i < n; i += 256) {
    const float4* Kr = (const float4*)(K + (size_t)i * (NUM_KV * HEAD_DIM));
    float a0 = 0.f, a1 = 0.f, a2 = 0.f, a3 = 0.f;
    #pragma unroll 8
    for (int dq = 0; dq < 32; dq++) {
      float4 k4 = Kr[dq];
      float4 q0 = *(const float4*)(ql + 4 * dq);
      float4 q1 = *(const float4*)(ql + 128 + 4 * dq);
      float4 q2 = *(const float4*)(ql + 256 + 4 * dq);
      float4 q3 = *(const float4*)(ql + 384 + 4 * dq);
      a0 += k4.x * q0.x + k4.y * q0.y + k4.z * q0.z + k4.w * q0.w;
      a1 += k4.x * q1.x + k4.y * q1.y + k4.z * q1.z + k4.w * q1.w;
      a2 += k4.x * q2.x + k4.y * q2.y + k4.z * q2.z + k4.w * q2.w;
      a3 += k4.x * q3.x + k4.y * q3.y + k4.z * q3.z + k4.w * q3.w;
    }
    sc[i]            = a0 * SCALEF;
    sc[SLEN + i]     = a1 * SCALEF;
    sc[2 * SLEN + i] = a2 * SCALEF;
    sc[3 * SLEN + i] = a3 * SCALEF;
  }
  __syncthreads();

  // online softmax stats, wave g owns head g; overwrite sc with exp(sc - m)
  float m = -INFINITY;
  for (int i = lane; i < n; i += 64) m = fmaxf(m, sc[g * SLEN + i]);
  #pragma unroll
  for (int off = 32; off; off >>= 1) m = fmaxf(m, __shfl_xor(m, off, 64));
  float lsum = 0.f;
  for (int i = lane; i < n; i += 64) {
    float e = __expf(sc[g * SLEN + i] - m);
    sc[g * SLEN + i] = e;
    lsum += e;
  }
  #pragma unroll
  for (int off = 32; off; off >>= 1) lsum += __shfl_xor(lsum, off, 64);
  __syncthreads();

  // phase B: o[d] = sum p[s] * V[s][d]; lane owns 2 d's, wave per head (V coalesced per wave)
  const float* V = kvc + ((((size_t)BSZ + b) * MAX_SEQ + s0) * NUM_KV + kvh) * HEAD_DIM + 2 * lane;
  float ox = 0.f, oy = 0.f;
  int i = 0;
  for (; i + 4 <= n; i += 4) {
    float p0 = sc[g * SLEN + i];
    float p1 = sc[g * SLEN + i + 1];
    float p2 = sc[g * SLEN + i + 2];
    float p3 = sc[g * SLEN + i + 3];
    float2 v0 = *(const float2*)(V + (size_t)i * 1024);
    float2 v1 = *(const float2*)(V + (size_t)(i + 1) * 1024);
    float2 v2 = *(const float2*)(V + (size_t)(i + 2) * 1024);
    float2 v3 = *(const float2*)(V + (size_t)(i + 3) * 1024);
    ox += p0 * v0.x + p1 * v1.x + p2 * v2.x + p3 * v3.x;
    oy += p0 * v0.y + p1 * v1.y + p2 * v2.y + p3 * v3.y;
  }
  for (; i < n; i++) {
    float p = sc[g * SLEN + i];
    float2 v0 = *(const float2*)(V + (size_t)i * 1024);
    ox += p * v0.x; oy += p * v0.y;
  }
  po[pbase * HEAD_DIM + 2 * lane]     = ox;
  po[pbase * HEAD_DIM + 2 * lane + 1] = oy;
  if (lane == 0) { pml[pbase * 2] = m; pml[pbase * 2 + 1] = lsum; }
}

// ---------------- combine split partials -------------------------------------------------------
__global__ __launch_bounds__(64) void combine_kernel(
    const float* __restrict__ po, const float* __restrict__ pml,
    float* __restrict__ attn_out)
{
  int hidx = blockIdx.x;       // b*32 + h
  int b = hidx >> 5, h = hidx & 31;
  int kvh = h >> 2, g = h & 3;
  int lane = threadIdx.x;

  float ms[NSPLIT_S], ls[NSPLIT_S];
  float m = -INFINITY;
  #pragma unroll
  for (int s = 0; s < NSPLIT_S; s++) {
    size_t pb = (((size_t)s * BSZ + b) * NUM_KV + kvh) * 4 + g;
    ms[s] = pml[pb * 2]; ls[s] = pml[pb * 2 + 1];
    m = fmaxf(m, ms[s]);
  }
  float L = 0.f, ox = 0.f, oy = 0.f;
  #pragma unroll
  for (int s = 0; s < NSPLIT_S; s++) {
    float w = __expf(ms[s] - m);
    L += ls[s] * w;
    size_t pb = (((size_t)s * BSZ + b) * NUM_KV + kvh) * 4 + g;
    ox += w * po[pb * HEAD_DIM + 2 * lane];
    oy += w * po[pb * HEAD_DIM + 2 * lane + 1];
  }
  float inv = 1.f / L;
  attn_out[(size_t)b * 4096 + h * HEAD_DIM + 2 * lane]     = ox * inv;
  attn_out[(size_t)b * 4096 + h * HEAD_DIM + 2 * lane + 1] = oy * inv;
}

// ---------------- finalize output projection ---------------------------------------------------
__global__ __launch_bounds__(256) void finalize_out(
    const float* __restrict__ part, float* __restrict__ out)
{
  int idx = blockIdx.x * 256 + threadIdx.x;  // 32*4096
  int b = idx >> 12, ii = idx & 4095;
  float v = part[((size_t)0 * BSZ + b) * 4096 + ii]
          + part[((size_t)1 * BSZ + b) * 4096 + ii]
          + part[((size_t)2 * BSZ + b) * 4096 + ii]
          + part[((size_t)3 * BSZ + b) * 4096 + ii];
  out[idx] = v;
}

extern "C" void kernel_launch(void* const* d_in, const int* in_sizes, int n_in,
                              void* d_out, int out_size, void* d_ws, size_t ws_size,
                              hipStream_t stream) {
  const float* hidden = (const float*)d_in[0];
  float* kvc          = (float*)d_in[2];     // written then read within this launch; harness restores
  const int* slot     = (const int*)d_in[3];
  const int* seq      = (const int*)d_in[4];
  const float* Wqkv   = (const float*)d_in[5];
  const float* bqkv   = (const float*)d_in[6];
  const float* Wo     = (const float*)d_in[7];
  float* out = (float*)d_out;
  float* ws  = (float*)d_ws;

  float* part1    = ws;              // 4*32*6144   = 786432
  float* qws      = ws + 786432;     // 32*4096     = 131072
  float* po       = ws + 917504;     // 8*32*8*4*128= 1048576
  float* pml      = ws + 1966080;    // 8*32*8*4*2  = 16384
  float* attn_out = ws + 1982464;    // 32*4096     = 131072
  float* part2    = ws + 2113536;    // 4*32*4096   = 524288

  gemv_bk<<<96 * 4, 256, 0, stream>>>(Wqkv, hidden, part1, QKV_OUT, 96);
  finalize_qkv<<<(BSZ * QKV_OUT) / 256, 256, 0, stream>>>(part1, bqkv, qws, kvc, slot);
  attn_kernel<<<BSZ * NUM_KV * NSPLIT_S, 256, 0, stream>>>(kvc, qws, seq, po, pml);
  combine_kernel<<<BSZ * 32, 64, 0, stream>>>(po, pml, attn_out);
  gemv_bk<<<64 * 4, 256, 0, stream>>>(Wo, attn_out, part2, 4096, 64);
  finalize_out<<<(BSZ * 4096) / 256, 256, 0, stream>>>(part2, out);
}